// Round 9
// baseline (250.686 us; speedup 1.0000x reference)
//
#include <hip/hip_runtime.h>
#include <math.h>

#define N_ATOMS 100000
#define N_EDGES 1600000
#define NSTRUCT 64
#define APB 128        // atoms per bucket
#define NBUCK 782      // ceil(N_ATOMS/APB)
#define EPB 8192       // edges per block in bucket passes
#define BCAP 3072      // LDS pair cap per bucket (mean 2048, std ~45)

__device__ __forceinline__ float frcp(float x) { return __builtin_amdgcn_rcpf(x); }
__device__ __forceinline__ float silu(float v) { return v * frcp(1.f + __expf(-v)); }

// ---------------- pack atom data: {mx,my,mz,px},{py,pz,mnorm,species} ----------------

__global__ void k_pack(const float* __restrict__ pos, const float* __restrict__ mmv,
                       const int* __restrict__ species, float* __restrict__ packed) {
    int a = blockIdx.x * 256 + threadIdx.x;
    if (a >= N_ATOMS) return;
    float mx = mmv[a * 3 + 0], my = mmv[a * 3 + 1], mz = mmv[a * 3 + 2];
    float px = pos[a * 3 + 0], py = pos[a * 3 + 1], pz = pos[a * 3 + 2];
    float mn = sqrtf(mx * mx + my * my + mz * mz + 1e-9f);
    float4* o = (float4*)packed;
    o[a * 2 + 0] = make_float4(mx, my, mz, px);
    o[a * 2 + 1] = make_float4(py, pz, mn, (float)species[a]);
}

// ---------------- prep: fold emb @ W-layer1 (+bias) per (species/head) ----------------

__global__ void k_prep(const float* __restrict__ embt,
                       const float* __restrict__ Wm1, const float* __restrict__ bm1,
                       const float* __restrict__ Ws1, const float* __restrict__ bs1,
                       float* __restrict__ c1m, float* __restrict__ c1s) {
    int tid = blockIdx.x * 256 + threadIdx.x;
    if (tid < 1152) {
        int h = tid >> 7;
        int sp = (tid >> 5) & 3;
        int o = tid & 31;
        float c = bm1[h * 32 + o];
#pragma unroll
        for (int q = 0; q < 16; q++)
            c = fmaf(embt[sp * 16 + q], Wm1[(h * 24 + 8 + q) * 32 + o], c);
        c1m[tid] = c;
    } else if (tid < 1152 + 256) {
        int k = tid - 1152;
        int sp = k >> 6, o = k & 63;
        float c = bs1[o];
#pragma unroll
        for (int q = 0; q < 16; q++)
            c = fmaf(embt[sp * 16 + q], Ws1[(16 + q) * 64 + o], c);
        c1s[k] = c;
    }
}

// ---------------- sort pass 1: coarse bucket histogram (LDS-aggregated) ----------------

__global__ __launch_bounds__(1024) void k_bhist(const int* __restrict__ i_idx,
                                                int* __restrict__ bucket_count) {
    __shared__ int h[NBUCK];
    int t = threadIdx.x;
    for (int k = t; k < NBUCK; k += 1024) h[k] = 0;
    __syncthreads();
    int base = blockIdx.x * EPB;
    for (int k = t; k < EPB; k += 1024) {
        int e = base + k;
        if (e < N_EDGES) atomicAdd(&h[i_idx[e] >> 7], 1);
    }
    __syncthreads();
    for (int k = t; k < NBUCK; k += 1024)
        if (h[k]) atomicAdd(&bucket_count[k], h[k]);
}

// ---------------- sort pass 2: scan bucket counts ----------------

__global__ __launch_bounds__(1024) void k_bscan(const int* __restrict__ bucket_count,
                                                int* __restrict__ bucket_start,
                                                int* __restrict__ bucket_cursor) {
    __shared__ int sd[1024];
    int t = threadIdx.x;
    int v0 = (t < NBUCK) ? bucket_count[t] : 0;
    sd[t] = v0;
    __syncthreads();
    for (int off = 1; off < 1024; off <<= 1) {
        int v = (t >= off) ? sd[t - off] : 0;
        __syncthreads();
        sd[t] += v;
        __syncthreads();
    }
    if (t < NBUCK) { int ex = sd[t] - v0; bucket_start[t] = ex; bucket_cursor[t] = ex; }
}

// ---------------- sort pass 3: scatter (i,j) pairs into bucket-major order ----------------

__global__ __launch_bounds__(1024) void k_bscatter(const int* __restrict__ i_idx,
                                                   const int* __restrict__ j_idx,
                                                   int* __restrict__ bucket_cursor,
                                                   uint2* __restrict__ ij_bucketed) {
    __shared__ int h[NBUCK];
    __shared__ int gbase[NBUCK];
    int t = threadIdx.x;
    for (int k = t; k < NBUCK; k += 1024) h[k] = 0;
    __syncthreads();
    int base = blockIdx.x * EPB;
    for (int k = t; k < EPB; k += 1024) {
        int e = base + k;
        if (e < N_EDGES) atomicAdd(&h[i_idx[e] >> 7], 1);
    }
    __syncthreads();
    for (int k = t; k < NBUCK; k += 1024) {
        int c = h[k];
        gbase[k] = c ? atomicAdd(&bucket_cursor[k], c) : 0;
        h[k] = 0;   // reuse as local cursor
    }
    __syncthreads();
    for (int k = t; k < EPB; k += 1024) {
        int e = base + k;
        if (e < N_EDGES) {
            int i = i_idx[e];
            int b = i >> 7;
            int r = atomicAdd(&h[b], 1);
            ij_bucketed[gbase[b] + r] = make_uint2((unsigned)i, (unsigned)j_idx[e]);
        }
    }
}

// ---------------- fused sort + edge compute + reduce: one block per bucket ----------------
// phase 1: exact per-atom sort of the bucket's pairs into LDS sp[]
// phase 2: 8 lanes/atom (128 atoms x 8 = 1024 threads), lane s owns phi-column s,
//          register accumulation straight from sp[], write segbuf. No records.

__global__ __launch_bounds__(1024) void k_fused(
    const int* __restrict__ bucket_start, const int* __restrict__ bucket_count,
    const uint2* __restrict__ ij_bucketed,
    const float* __restrict__ packed, const float* __restrict__ cheb,
    float* __restrict__ segbuf) {
    __shared__ int ac[APB];
    __shared__ int st[APB];
    __shared__ int rs[APB];
    __shared__ uint2 sp[BCAP];        // 24 KB
    __shared__ float4 apk[APB * 2];   // 4 KB
    int b = blockIdx.x, t = threadIdx.x;
    int estart = bucket_start[b], nb = bucket_count[b];
    if (nb > BCAP) nb = BCAP;   // statistically impossible; guards LDS
    int abase = b * APB;
    const float4* pk4 = (const float4*)packed;

    if (t < APB * 2) {
        int a = abase + (t >> 1);
        apk[t] = (a < N_ATOMS) ? pk4[a * 2 + (t & 1)] : make_float4(0.f, 0.f, 1.f, 0.f);
    }
    if (t < APB) ac[t] = 0;
    __syncthreads();
    for (int k = t; k < nb; k += 1024)
        atomicAdd(&ac[ij_bucketed[estart + k].x - abase], 1);
    __syncthreads();
    if (t < APB) st[t] = ac[t];
    __syncthreads();
    for (int off = 1; off < APB; off <<= 1) {
        int v = 0;
        if (t < APB && t >= off) v = st[t - off];
        __syncthreads();
        if (t < APB) st[t] += v;
        __syncthreads();
    }
    if (t < APB) {
        int ex = st[t] - ac[t];
        rs[t] = ex;
        ac[t] = ex;   // reuse as cursor
    }
    __syncthreads();
    for (int k = t; k < nb; k += 1024) {
        uint2 p = ij_bucketed[estart + k];
        int r = atomicAdd(&ac[p.x - abase], 1);
        sp[r] = p;
    }
    __syncthreads();

    // ---- reduce phase ----
    int g = t >> 3, s = t & 7;
    int a = abase + g;
    if (a >= N_ATOMS) return;

    float4 i0 = apk[g * 2 + 0], i1 = apk[g * 2 + 1];
    float mix = i0.x, miy = i0.y, miz = i0.z;
    float pix = i0.w, piy = i1.x, piz = i1.y;
    float mni = i1.z;
    int spi = (int)i1.w;
    float inv_mni = frcp(mni);
    float mhix = mix * inv_mni, mhiy = miy * inv_mni, mhiz = miz * inv_mni;
    const float* cbase = cheb + spi * 4 * 96 + s * 12;

    float sg0 = 0.f, sg1 = 0.f, sg2 = 0.f, sg3 = 0.f;
    float sg4 = 0.f, sg5 = 0.f, sg6 = 0.f, sg7 = 0.f;
    float vcx = 0.f, vcy = 0.f, vcz = 0.f;

    int r0 = rs[g], r1 = st[g];
    for (int k = r0; k < r1; ++k) {
        int j = (int)sp[k].y;
        float4 j0 = pk4[j * 2 + 0];
        float4 j1 = pk4[j * 2 + 1];
        float mjx = j0.x, mjy = j0.y, mjz = j0.z;
        float rx = j0.w - pix, ry = j1.x - piy, rz = j1.y - piz;
        float mnj = j1.z;
        int spj = (int)j1.w;

        const float4* c4 = (const float4*)(cbase + spj * 96);
        float4 c0 = c4[0], c1 = c4[1], c2 = c4[2];

        float d = sqrtf(rx * rx + ry * ry + rz * rz + 1e-9f);
        float invd = frcp(d);
        float rhx = rx * invd, rhy = ry * invd, rhz = rz * invd;

        float x = d * (1.f / 3.f) - 1.f;
        x = fminf(fmaxf(x, -1.f), 1.f);
        float x2 = 2.f * x;
        float T0 = 1.f, T1 = x;
        float T2 = x2 * T1 - T0, T3 = x2 * T2 - T1, T4 = x2 * T3 - T2, T5 = x2 * T4 - T3;
        float T6 = x2 * T5 - T4, T7 = x2 * T6 - T5, T8 = x2 * T7 - T6, T9 = x2 * T8 - T7;
        float T10 = x2 * T9 - T8, T11 = x2 * T10 - T9;
        float fcut = (d < 6.f) ? 0.5f * (__cosf(d * 0.52359877559829887f) + 1.f) : 0.f;

        float phis = c0.x * T0 + c0.y * T1 + c0.z * T2 + c0.w * T3;
        phis += c1.x * T4 + c1.y * T5 + c1.z * T6 + c1.w * T7;
        phis += c2.x * T8 + c2.y * T9 + c2.z * T10 + c2.w * T11;
        phis *= fcut;

        float invmnj = frcp(mnj);
        float mhjx = mjx * invmnj, mhjy = mjy * invmnj, mhjz = mjz * invmnj;
        float w1 = mix * mjx + miy * mjy + miz * mjz;
        float dhi = mhix * rhx + mhiy * rhy + mhiz * rhz;
        float dhj = mhjx * rhx + mhjy * rhy + mhjz * rhz;
        float w2 = dhi * dhi, w3 = dhj * dhj;
        float cx = miy * mjz - miz * mjy;
        float cy = miz * mjx - mix * mjz;
        float cz = mix * mjy - miy * mjx;
        float w4 = rhx * cx + rhy * cy + rhz * cz;
        float w6 = (mhix * mhjx + mhiy * mhjy + mhiz * mhjz) * mnj;
        float w7 = mnj * mnj;

        sg0 += phis;
        sg1 = fmaf(w1, phis, sg1);
        sg2 = fmaf(w2, phis, sg2);
        sg3 = fmaf(w3, phis, sg3);
        sg4 = fmaf(w4, phis, sg4);
        sg5 = fmaf(mnj, phis, sg5);
        sg6 = fmaf(w6, phis, sg6);
        sg7 = fmaf(w7, phis, sg7);
        vcx = fmaf(phis, rhx, vcx);
        vcy = fmaf(phis, rhy, vcy);
        vcz = fmaf(phis, rhz, vcz);
    }

    float* o = segbuf + (size_t)a * 72;
    o[0 * 8 + s] = sg0; o[1 * 8 + s] = sg1; o[2 * 8 + s] = sg2; o[3 * 8 + s] = sg3;
    o[4 * 8 + s] = sg4; o[5 * 8 + s] = sg5; o[6 * 8 + s] = sg6; o[7 * 8 + s] = sg7;
    o[64 + s] = vcx * vcx + vcy * vcy + vcz * vcz;
}

// ---------------- structure MLP: thread=atom, chunked layer-2, uniform s_load weights ----------------

__global__ __launch_bounds__(256, 4) void k_struct(
    const float* __restrict__ segbuf, const int* __restrict__ species,
    const int* __restrict__ batch, const float* __restrict__ c1s,
    const float* __restrict__ shift,
    const float* __restrict__ Ws1,
    const float* __restrict__ Ws2, const float* __restrict__ bs2,
    const float* __restrict__ Ws3, const float* __restrict__ bs3,
    float* __restrict__ out) {
    __shared__ float spart[NSTRUCT];
    int t = threadIdx.x;
    if (t < NSTRUCT) spart[t] = 0.f;
    __syncthreads();

    int a = blockIdx.x * 256 + t;
    if (a < N_ATOMS) {
        const float4* sb4 = (const float4*)(segbuf + (size_t)a * 72);
        float4 v0 = sb4[0], v1 = sb4[1];
        float4 v2 = sb4[16], v3 = sb4[17];
        int spi = species[a];
        float x[16] = {v0.x, v0.y, v0.z, v0.w, v1.x, v1.y, v1.z, v1.w,
                       v2.x, v2.y, v2.z, v2.w, v3.x, v3.y, v3.z, v3.w};

        const float* cb = c1s + spi * 64;
        float h1[64];
#pragma unroll
        for (int o = 0; o < 64; o++) h1[o] = cb[o];
#pragma unroll
        for (int k = 0; k < 16; k++) {
            float xv = x[k];
#pragma unroll
            for (int o = 0; o < 64; o++) h1[o] = fmaf(xv, Ws1[k * 64 + o], h1[o]);
        }
#pragma unroll
        for (int o = 0; o < 64; o++) h1[o] = silu(h1[o]);

        float e_struct = bs3[0] + shift[spi];
#pragma unroll 1
        for (int cbk = 0; cbk < 4; cbk++) {
            float h2[16];
#pragma unroll
            for (int o = 0; o < 16; o++) h2[o] = bs2[cbk * 16 + o];
#pragma unroll 4
            for (int k = 0; k < 64; k++) {
                float xv = h1[k];
#pragma unroll
                for (int o = 0; o < 16; o++)
                    h2[o] = fmaf(xv, Ws2[k * 64 + cbk * 16 + o], h2[o]);
            }
#pragma unroll
            for (int o = 0; o < 16; o++)
                e_struct = fmaf(silu(h2[o]), Ws3[cbk * 16 + o], e_struct);
        }
        atomicAdd(&spart[batch[a]], e_struct);
    }
    __syncthreads();
    if (t < NSTRUCT) {
        float v = spart[t];
        if (v != 0.f) atomicAdd(&out[t], v);
    }
}

// ---------------- magnetic MLP: grid.y = head (truly uniform), chunked layer-2 ----------------

__global__ __launch_bounds__(256, 4) void k_mag(
    const float* __restrict__ segbuf, const float* __restrict__ packed,
    const int* __restrict__ species, const int* __restrict__ batch,
    const float* __restrict__ c1m,
    const float* __restrict__ Wm1,
    const float* __restrict__ Wm2, const float* __restrict__ bm2,
    const float* __restrict__ Wm3, const float* __restrict__ bm3,
    float* __restrict__ out) {
    __shared__ float spart[NSTRUCT];
    int t = threadIdx.x;
    if (t < NSTRUCT) spart[t] = 0.f;
    __syncthreads();

    int h = blockIdx.y;                 // grid-uniform head index
    int a = blockIdx.x * 256 + t;
    if (a < N_ATOMS) {
        int kk = (h <= 5) ? h : (h - 1);
        const float4* sb4 = (const float4*)(segbuf + (size_t)a * 72 + kk * 8);
        float4 s0 = sb4[0], s1 = sb4[1];
        float amp = (h == 0 || h == 5) ? packed[a * 8 + 6] : 1.f;
        float x[8] = {s0.x * amp, s0.y * amp, s0.z * amp, s0.w * amp,
                      s1.x * amp, s1.y * amp, s1.z * amp, s1.w * amp};
        int spi = species[a];

        const float* cb1 = c1m + (h * 4 + spi) * 32;
        float hm1[32];
#pragma unroll
        for (int o = 0; o < 32; o++) hm1[o] = cb1[o];
        const float* wb1 = Wm1 + h * 768;
#pragma unroll
        for (int d = 0; d < 8; d++) {
            float xv = x[d];
#pragma unroll
            for (int o = 0; o < 32; o++) hm1[o] = fmaf(xv, wb1[d * 32 + o], hm1[o]);
        }
#pragma unroll
        for (int o = 0; o < 32; o++) hm1[o] = silu(hm1[o]);

        const float* wb2 = Wm2 + h * 1024;
        float e_head = bm3[h];
#pragma unroll 1
        for (int cbk = 0; cbk < 2; cbk++) {
            float h2[16];
#pragma unroll
            for (int o = 0; o < 16; o++) h2[o] = bm2[h * 32 + cbk * 16 + o];
#pragma unroll 4
            for (int d = 0; d < 32; d++) {
                float xv = hm1[d];
#pragma unroll
                for (int o = 0; o < 16; o++)
                    h2[o] = fmaf(xv, wb2[d * 32 + cbk * 16 + o], h2[o]);
            }
#pragma unroll
            for (int o = 0; o < 16; o++)
                e_head = fmaf(silu(h2[o]), Wm3[h * 32 + cbk * 16 + o], e_head);
        }
        atomicAdd(&spart[batch[a]], e_head);
    }
    __syncthreads();
    if (t < NSTRUCT) {
        float v = spart[t];
        if (v != 0.f) atomicAdd(&out[t], v);
    }
}

// ---------------- launch ----------------

extern "C" void kernel_launch(void* const* d_in, const int* in_sizes, int n_in,
                              void* d_out, int out_size, void* d_ws, size_t ws_size,
                              hipStream_t stream) {
    const float* pos   = (const float*)d_in[0];
    const float* mmv   = (const float*)d_in[1];
    const int* species = (const int*)d_in[2];
    const int* i_idx   = (const int*)d_in[3];
    const int* j_idx   = (const int*)d_in[4];
    const int* batch   = (const int*)d_in[5];
    const float* cheb  = (const float*)d_in[6];
    const float* embt  = (const float*)d_in[7];
    const float* shift = (const float*)d_in[8];
    const float* Ws1 = (const float*)d_in[9];
    const float* bs1 = (const float*)d_in[10];
    const float* Ws2 = (const float*)d_in[11];
    const float* bs2 = (const float*)d_in[12];
    const float* Ws3 = (const float*)d_in[13];
    const float* bs3 = (const float*)d_in[14];
    const float* Wm1 = (const float*)d_in[15];
    const float* bm1 = (const float*)d_in[16];
    const float* Wm2 = (const float*)d_in[17];
    const float* bm2 = (const float*)d_in[18];
    const float* Wm3 = (const float*)d_in[19];
    const float* bm3 = (const float*)d_in[20];
    float* out = (float*)d_out;

    char* ws = (char*)d_ws;
    int* bucket_count  = (int*)(ws + 0);          // 3.1 KB
    int* bucket_start  = (int*)(ws + 4096);       // 3.1 KB
    int* bucket_cursor = (int*)(ws + 8192);       // 3.1 KB
    float* c1m         = (float*)(ws + 12288);    // 4.6 KB
    float* c1s         = (float*)(ws + 16896);    // 1 KB
    float* packed      = (float*)(ws + 20480);    // 3.2 MB
    float* segbuf      = (float*)(ws + 3220480);  // 28.8 MB
    uint2* ij_bucketed = (uint2*)(ws + 32020480); // 12.8 MB (end ~44.8 MB)

    const int NB_ATOM = (N_ATOMS + 255) / 256;     // 391
    const int NB_EPB  = (N_EDGES + EPB - 1) / EPB; // 196

    hipMemsetAsync(bucket_count, 0, NBUCK * sizeof(int), stream);
    hipMemsetAsync(out, 0, NSTRUCT * sizeof(float), stream);

    k_pack<<<NB_ATOM, 256, 0, stream>>>(pos, mmv, species, packed);
    k_prep<<<6, 256, 0, stream>>>(embt, Wm1, bm1, Ws1, bs1, c1m, c1s);
    k_bhist<<<NB_EPB, 1024, 0, stream>>>(i_idx, bucket_count);
    k_bscan<<<1, 1024, 0, stream>>>(bucket_count, bucket_start, bucket_cursor);
    k_bscatter<<<NB_EPB, 1024, 0, stream>>>(i_idx, j_idx, bucket_cursor, ij_bucketed);
    k_fused<<<NBUCK, 1024, 0, stream>>>(bucket_start, bucket_count, ij_bucketed,
                                        packed, cheb, segbuf);
    k_struct<<<NB_ATOM, 256, 0, stream>>>(segbuf, species, batch, c1s, shift,
                                          Ws1, Ws2, bs2, Ws3, bs3, out);
    dim3 magGrid(NB_ATOM, 9);
    k_mag<<<magGrid, 256, 0, stream>>>(segbuf, packed, species, batch, c1m,
                                       Wm1, Wm2, bm2, Wm3, bm3, out);
}

// Round 10
// 231.609 us; speedup vs baseline: 1.0824x; 1.0824x over previous
//
#include <hip/hip_runtime.h>
#include <math.h>

#define N_ATOMS 100000
#define N_EDGES 1600000
#define NSTRUCT 64
#define APB 64         // atoms per bucket
#define NBUCK 1563     // ceil(N_ATOMS/APB)
#define EPB 8192       // edges per block in bucket passes
#define BCAP 1536      // LDS j cap per bucket (mean 1024, std ~32)

__device__ __forceinline__ float frcp(float x) { return __builtin_amdgcn_rcpf(x); }
__device__ __forceinline__ float silu(float v) { return v * frcp(1.f + __expf(-v)); }

// ---------------- pack atom data: {mx,my,mz,px},{py,pz,mnorm,species} ----------------

__global__ void k_pack(const float* __restrict__ pos, const float* __restrict__ mmv,
                       const int* __restrict__ species, float* __restrict__ packed) {
    int a = blockIdx.x * 256 + threadIdx.x;
    if (a >= N_ATOMS) return;
    float mx = mmv[a * 3 + 0], my = mmv[a * 3 + 1], mz = mmv[a * 3 + 2];
    float px = pos[a * 3 + 0], py = pos[a * 3 + 1], pz = pos[a * 3 + 2];
    float mn = sqrtf(mx * mx + my * my + mz * mz + 1e-9f);
    float4* o = (float4*)packed;
    o[a * 2 + 0] = make_float4(mx, my, mz, px);
    o[a * 2 + 1] = make_float4(py, pz, mn, (float)species[a]);
}

// ---------------- prep: fold emb @ W-layer1 (+bias) per (species/head) ----------------

__global__ void k_prep(const float* __restrict__ embt,
                       const float* __restrict__ Wm1, const float* __restrict__ bm1,
                       const float* __restrict__ Ws1, const float* __restrict__ bs1,
                       float* __restrict__ c1m, float* __restrict__ c1s) {
    int tid = blockIdx.x * 256 + threadIdx.x;
    if (tid < 1152) {
        int h = tid >> 7;
        int sp = (tid >> 5) & 3;
        int o = tid & 31;
        float c = bm1[h * 32 + o];
#pragma unroll
        for (int q = 0; q < 16; q++)
            c = fmaf(embt[sp * 16 + q], Wm1[(h * 24 + 8 + q) * 32 + o], c);
        c1m[tid] = c;
    } else if (tid < 1152 + 256) {
        int k = tid - 1152;
        int sp = k >> 6, o = k & 63;
        float c = bs1[o];
#pragma unroll
        for (int q = 0; q < 16; q++)
            c = fmaf(embt[sp * 16 + q], Ws1[(16 + q) * 64 + o], c);
        c1s[k] = c;
    }
}

// ---------------- sort pass 1: coarse bucket histogram (LDS-aggregated) ----------------

__global__ __launch_bounds__(1024) void k_bhist(const int* __restrict__ i_idx,
                                                int* __restrict__ bucket_count) {
    __shared__ int h[NBUCK];
    int t = threadIdx.x;
    for (int k = t; k < NBUCK; k += 1024) h[k] = 0;
    __syncthreads();
    int base = blockIdx.x * EPB;
    for (int k = t; k < EPB; k += 1024) {
        int e = base + k;
        if (e < N_EDGES) atomicAdd(&h[i_idx[e] >> 6], 1);
    }
    __syncthreads();
    for (int k = t; k < NBUCK; k += 1024)
        if (h[k]) atomicAdd(&bucket_count[k], h[k]);
}

// ---------------- sort pass 2: scan bucket counts (2 elems/thread Hillis-Steele) ----------------

__global__ __launch_bounds__(1024) void k_bscan(const int* __restrict__ bucket_count,
                                                int* __restrict__ bucket_start,
                                                int* __restrict__ bucket_cursor) {
    __shared__ int sd[2048];
    int t = threadIdx.x;
    int i0 = t, i1 = t + 1024;
    int a0 = (i0 < NBUCK) ? bucket_count[i0] : 0;
    int a1 = (i1 < NBUCK) ? bucket_count[i1] : 0;
    sd[i0] = a0; sd[i1] = a1;
    __syncthreads();
    for (int off = 1; off < 2048; off <<= 1) {
        int v0 = (i0 >= off) ? sd[i0 - off] : 0;
        int v1 = (i1 >= off) ? sd[i1 - off] : 0;
        __syncthreads();
        sd[i0] += v0; sd[i1] += v1;
        __syncthreads();
    }
    if (i0 < NBUCK) { int ex = sd[i0] - a0; bucket_start[i0] = ex; bucket_cursor[i0] = ex; }
    if (i1 < NBUCK) { int ex = sd[i1] - a1; bucket_start[i1] = ex; bucket_cursor[i1] = ex; }
}

// ---------------- sort pass 3: scatter (i,j) pairs into bucket-major order ----------------

__global__ __launch_bounds__(1024) void k_bscatter(const int* __restrict__ i_idx,
                                                   const int* __restrict__ j_idx,
                                                   int* __restrict__ bucket_cursor,
                                                   uint2* __restrict__ ij_bucketed) {
    __shared__ int h[NBUCK];
    __shared__ int gbase[NBUCK];
    int t = threadIdx.x;
    for (int k = t; k < NBUCK; k += 1024) h[k] = 0;
    __syncthreads();
    int base = blockIdx.x * EPB;
    for (int k = t; k < EPB; k += 1024) {
        int e = base + k;
        if (e < N_EDGES) atomicAdd(&h[i_idx[e] >> 6], 1);
    }
    __syncthreads();
    for (int k = t; k < NBUCK; k += 1024) {
        int c = h[k];
        gbase[k] = c ? atomicAdd(&bucket_cursor[k], c) : 0;
        h[k] = 0;   // reuse as local cursor
    }
    __syncthreads();
    for (int k = t; k < EPB; k += 1024) {
        int e = base + k;
        if (e < N_EDGES) {
            int i = i_idx[e];
            int b = i >> 6;
            int r = atomicAdd(&h[b], 1);
            ij_bucketed[gbase[b] + r] = make_uint2((unsigned)i, (unsigned)j_idx[e]);
        }
    }
}

// ---------------- fused sort + edge compute + reduce: one block per bucket ----------------

__global__ __launch_bounds__(512) void k_fused(
    const int* __restrict__ bucket_start, const int* __restrict__ bucket_count,
    const uint2* __restrict__ ij_bucketed,
    const float* __restrict__ packed, const float* __restrict__ cheb,
    float* __restrict__ segbuf) {
    __shared__ int ac[APB];
    __shared__ int st[APB];
    __shared__ int rs[APB];
    __shared__ unsigned spj[BCAP];    // 6 KB (j only)
    __shared__ float4 apk[APB * 2];   // 2 KB
    int b = blockIdx.x, t = threadIdx.x;
    int estart = bucket_start[b], nb = bucket_count[b];
    if (nb > BCAP) nb = BCAP;   // statistically impossible; guards LDS
    int abase = b * APB;
    const float4* pk4 = (const float4*)packed;

    if (t < APB * 2) {
        int a = abase + (t >> 1);
        apk[t] = (a < N_ATOMS) ? pk4[a * 2 + (t & 1)] : make_float4(0.f, 0.f, 1.f, 0.f);
    }
    if (t < APB) ac[t] = 0;
    __syncthreads();
    for (int k = t; k < nb; k += 512)
        atomicAdd(&ac[ij_bucketed[estart + k].x - abase], 1);
    __syncthreads();
    if (t < APB) st[t] = ac[t];
    __syncthreads();
    for (int off = 1; off < APB; off <<= 1) {
        int v = 0;
        if (t < APB && t >= off) v = st[t - off];
        __syncthreads();
        if (t < APB) st[t] += v;
        __syncthreads();
    }
    if (t < APB) {
        int ex = st[t] - ac[t];
        rs[t] = ex;
        ac[t] = ex;   // reuse as cursor
    }
    __syncthreads();
    for (int k = t; k < nb; k += 512) {
        uint2 p = ij_bucketed[estart + k];
        int r = atomicAdd(&ac[p.x - abase], 1);
        spj[r] = p.y;
    }
    __syncthreads();

    // ---- reduce phase: 8 lanes/atom, lane s owns phi-column s ----
    int g = t >> 3, s = t & 7;
    int a = abase + g;
    if (a >= N_ATOMS) return;

    float4 i0 = apk[g * 2 + 0], i1 = apk[g * 2 + 1];
    float mix = i0.x, miy = i0.y, miz = i0.z;
    float pix = i0.w, piy = i1.x, piz = i1.y;
    float mni = i1.z;
    int spi = (int)i1.w;
    float inv_mni = frcp(mni);
    float mhix = mix * inv_mni, mhiy = miy * inv_mni, mhiz = miz * inv_mni;
    const float* cbase = cheb + spi * 4 * 96 + s * 12;

    float sg0 = 0.f, sg1 = 0.f, sg2 = 0.f, sg3 = 0.f;
    float sg4 = 0.f, sg5 = 0.f, sg6 = 0.f, sg7 = 0.f;
    float vcx = 0.f, vcy = 0.f, vcz = 0.f;

    int r0 = rs[g], r1 = st[g];
    int jn = (r0 < r1) ? (int)spj[r0] : 0;
    float4 j0n = pk4[jn * 2 + 0];
    float4 j1n = pk4[jn * 2 + 1];
    for (int k = r0; k < r1; ++k) {
        float4 a0 = j0n, a1 = j1n;
        if (k + 1 < r1) {
            jn = (int)spj[k + 1];
            j0n = pk4[jn * 2 + 0];
            j1n = pk4[jn * 2 + 1];
        }
        float mjx = a0.x, mjy = a0.y, mjz = a0.z;
        float rx = a0.w - pix, ry = a1.x - piy, rz = a1.y - piz;
        float mnj = a1.z;
        int spj_sp = (int)a1.w;

        const float4* c4 = (const float4*)(cbase + spj_sp * 96);
        float4 c0 = c4[0], c1 = c4[1], c2 = c4[2];

        float d = sqrtf(rx * rx + ry * ry + rz * rz + 1e-9f);
        float invd = frcp(d);
        float rhx = rx * invd, rhy = ry * invd, rhz = rz * invd;

        float x = d * (1.f / 3.f) - 1.f;
        x = fminf(fmaxf(x, -1.f), 1.f);
        float x2 = 2.f * x;
        float T0 = 1.f, T1 = x;
        float T2 = x2 * T1 - T0, T3 = x2 * T2 - T1, T4 = x2 * T3 - T2, T5 = x2 * T4 - T3;
        float T6 = x2 * T5 - T4, T7 = x2 * T6 - T5, T8 = x2 * T7 - T6, T9 = x2 * T8 - T7;
        float T10 = x2 * T9 - T8, T11 = x2 * T10 - T9;
        float fcut = (d < 6.f) ? 0.5f * (__cosf(d * 0.52359877559829887f) + 1.f) : 0.f;

        float phis = c0.x * T0 + c0.y * T1 + c0.z * T2 + c0.w * T3;
        phis += c1.x * T4 + c1.y * T5 + c1.z * T6 + c1.w * T7;
        phis += c2.x * T8 + c2.y * T9 + c2.z * T10 + c2.w * T11;
        phis *= fcut;

        float invmnj = frcp(mnj);
        float mhjx = mjx * invmnj, mhjy = mjy * invmnj, mhjz = mjz * invmnj;
        float w1 = mix * mjx + miy * mjy + miz * mjz;
        float dhi = mhix * rhx + mhiy * rhy + mhiz * rhz;
        float dhj = mhjx * rhx + mhjy * rhy + mhjz * rhz;
        float w2 = dhi * dhi, w3 = dhj * dhj;
        float cx = miy * mjz - miz * mjy;
        float cy = miz * mjx - mix * mjz;
        float cz = mix * mjy - miy * mjx;
        float w4 = rhx * cx + rhy * cy + rhz * cz;
        float w6 = (mhix * mhjx + mhiy * mhjy + mhiz * mhjz) * mnj;
        float w7 = mnj * mnj;

        sg0 += phis;
        sg1 = fmaf(w1, phis, sg1);
        sg2 = fmaf(w2, phis, sg2);
        sg3 = fmaf(w3, phis, sg3);
        sg4 = fmaf(w4, phis, sg4);
        sg5 = fmaf(mnj, phis, sg5);
        sg6 = fmaf(w6, phis, sg6);
        sg7 = fmaf(w7, phis, sg7);
        vcx = fmaf(phis, rhx, vcx);
        vcy = fmaf(phis, rhy, vcy);
        vcz = fmaf(phis, rhz, vcz);
    }

    float* o = segbuf + (size_t)a * 72;
    o[0 * 8 + s] = sg0; o[1 * 8 + s] = sg1; o[2 * 8 + s] = sg2; o[3 * 8 + s] = sg3;
    o[4 * 8 + s] = sg4; o[5 * 8 + s] = sg5; o[6 * 8 + s] = sg6; o[7 * 8 + s] = sg7;
    o[64 + s] = vcx * vcx + vcy * vcy + vcz * vcz;
}

// ---------------- structure MLP: thread=atom, FULLY static unroll (no scratch) ----------------

__global__ __launch_bounds__(256) void k_struct(
    const float* __restrict__ segbuf, const int* __restrict__ species,
    const int* __restrict__ batch, const float* __restrict__ c1s,
    const float* __restrict__ shift,
    const float* __restrict__ Ws1,
    const float* __restrict__ Ws2, const float* __restrict__ bs2,
    const float* __restrict__ Ws3, const float* __restrict__ bs3,
    float* __restrict__ out) {
    __shared__ float spart[NSTRUCT];
    int t = threadIdx.x;
    if (t < NSTRUCT) spart[t] = 0.f;
    __syncthreads();

    int a = blockIdx.x * 256 + t;
    if (a < N_ATOMS) {
        const float4* sb4 = (const float4*)(segbuf + (size_t)a * 72);
        float4 v0 = sb4[0], v1 = sb4[1];
        float4 v2 = sb4[16], v3 = sb4[17];
        int spi = species[a];
        float x[16] = {v0.x, v0.y, v0.z, v0.w, v1.x, v1.y, v1.z, v1.w,
                       v2.x, v2.y, v2.z, v2.w, v3.x, v3.y, v3.z, v3.w};

        float h1[64];
        const float4* cb4 = (const float4*)(c1s + spi * 64);
#pragma unroll
        for (int q = 0; q < 16; q++) {
            float4 c = cb4[q];
            h1[q * 4 + 0] = c.x; h1[q * 4 + 1] = c.y;
            h1[q * 4 + 2] = c.z; h1[q * 4 + 3] = c.w;
        }
#pragma unroll
        for (int k = 0; k < 16; k++) {
            float xv = x[k];
#pragma unroll
            for (int o = 0; o < 64; o++) h1[o] = fmaf(xv, Ws1[k * 64 + o], h1[o]);
        }
#pragma unroll
        for (int o = 0; o < 64; o++) h1[o] = silu(h1[o]);

        float e_struct = bs3[0] + shift[spi];
#pragma unroll
        for (int cbk = 0; cbk < 4; cbk++) {
            float h2[16];
#pragma unroll
            for (int o = 0; o < 16; o++) h2[o] = bs2[cbk * 16 + o];
#pragma unroll
            for (int k = 0; k < 64; k++) {
                float xv = h1[k];
#pragma unroll
                for (int o = 0; o < 16; o++)
                    h2[o] = fmaf(xv, Ws2[k * 64 + cbk * 16 + o], h2[o]);
            }
#pragma unroll
            for (int o = 0; o < 16; o++)
                e_struct = fmaf(silu(h2[o]), Ws3[cbk * 16 + o], e_struct);
        }
        atomicAdd(&spart[batch[a]], e_struct);
    }
    __syncthreads();
    if (t < NSTRUCT) {
        float v = spart[t];
        if (v != 0.f) atomicAdd(&out[t], v);
    }
}

// ---------------- magnetic MLP: thread=atom, head=blockIdx.y, FULLY static unroll ----------------

__global__ __launch_bounds__(256) void k_mag(
    const float* __restrict__ segbuf, const float* __restrict__ packed,
    const int* __restrict__ species, const int* __restrict__ batch,
    const float* __restrict__ c1m,
    const float* __restrict__ Wm1,
    const float* __restrict__ Wm2, const float* __restrict__ bm2,
    const float* __restrict__ Wm3, const float* __restrict__ bm3,
    float* __restrict__ out) {
    __shared__ float spart[NSTRUCT];
    int t = threadIdx.x;
    if (t < NSTRUCT) spart[t] = 0.f;
    __syncthreads();

    int h = blockIdx.y;                 // grid-uniform head index
    int a = blockIdx.x * 256 + t;
    if (a < N_ATOMS) {
        int kk = (h <= 5) ? h : (h - 1);
        const float4* sb4 = (const float4*)(segbuf + (size_t)a * 72 + kk * 8);
        float4 s0 = sb4[0], s1 = sb4[1];
        float amp = (h == 0 || h == 5) ? packed[a * 8 + 6] : 1.f;
        float x[8] = {s0.x * amp, s0.y * amp, s0.z * amp, s0.w * amp,
                      s1.x * amp, s1.y * amp, s1.z * amp, s1.w * amp};
        int spi = species[a];

        float hm1[32];
        const float4* cb4 = (const float4*)(c1m + (h * 4 + spi) * 32);
#pragma unroll
        for (int q = 0; q < 8; q++) {
            float4 c = cb4[q];
            hm1[q * 4 + 0] = c.x; hm1[q * 4 + 1] = c.y;
            hm1[q * 4 + 2] = c.z; hm1[q * 4 + 3] = c.w;
        }
        const float* wb1 = Wm1 + h * 768;
#pragma unroll
        for (int d = 0; d < 8; d++) {
            float xv = x[d];
#pragma unroll
            for (int o = 0; o < 32; o++) hm1[o] = fmaf(xv, wb1[d * 32 + o], hm1[o]);
        }
#pragma unroll
        for (int o = 0; o < 32; o++) hm1[o] = silu(hm1[o]);

        const float* wb2 = Wm2 + h * 1024;
        float e_head = bm3[h];
#pragma unroll
        for (int cbk = 0; cbk < 2; cbk++) {
            float h2[16];
#pragma unroll
            for (int o = 0; o < 16; o++) h2[o] = bm2[h * 32 + cbk * 16 + o];
#pragma unroll
            for (int d = 0; d < 32; d++) {
                float xv = hm1[d];
#pragma unroll
                for (int o = 0; o < 16; o++)
                    h2[o] = fmaf(xv, wb2[d * 32 + cbk * 16 + o], h2[o]);
            }
#pragma unroll
            for (int o = 0; o < 16; o++)
                e_head = fmaf(silu(h2[o]), Wm3[h * 32 + cbk * 16 + o], e_head);
        }
        atomicAdd(&spart[batch[a]], e_head);
    }
    __syncthreads();
    if (t < NSTRUCT) {
        float v = spart[t];
        if (v != 0.f) atomicAdd(&out[t], v);
    }
}

// ---------------- launch ----------------

extern "C" void kernel_launch(void* const* d_in, const int* in_sizes, int n_in,
                              void* d_out, int out_size, void* d_ws, size_t ws_size,
                              hipStream_t stream) {
    const float* pos   = (const float*)d_in[0];
    const float* mmv   = (const float*)d_in[1];
    const int* species = (const int*)d_in[2];
    const int* i_idx   = (const int*)d_in[3];
    const int* j_idx   = (const int*)d_in[4];
    const int* batch   = (const int*)d_in[5];
    const float* cheb  = (const float*)d_in[6];
    const float* embt  = (const float*)d_in[7];
    const float* shift = (const float*)d_in[8];
    const float* Ws1 = (const float*)d_in[9];
    const float* bs1 = (const float*)d_in[10];
    const float* Ws2 = (const float*)d_in[11];
    const float* bs2 = (const float*)d_in[12];
    const float* Ws3 = (const float*)d_in[13];
    const float* bs3 = (const float*)d_in[14];
    const float* Wm1 = (const float*)d_in[15];
    const float* bm1 = (const float*)d_in[16];
    const float* Wm2 = (const float*)d_in[17];
    const float* bm2 = (const float*)d_in[18];
    const float* Wm3 = (const float*)d_in[19];
    const float* bm3 = (const float*)d_in[20];
    float* out = (float*)d_out;

    char* ws = (char*)d_ws;
    int* bucket_count  = (int*)(ws + 0);          // 6.3 KB
    int* bucket_start  = (int*)(ws + 8192);       // 6.3 KB
    int* bucket_cursor = (int*)(ws + 16384);      // 6.3 KB
    float* c1m         = (float*)(ws + 24576);    // 4.6 KB
    float* c1s         = (float*)(ws + 29184);    // 1 KB
    float* packed      = (float*)(ws + 32768);    // 3.2 MB
    float* segbuf      = (float*)(ws + 3232768);  // 28.8 MB
    uint2* ij_bucketed = (uint2*)(ws + 32032768); // 12.8 MB (end ~44.8 MB)

    const int NB_ATOM = (N_ATOMS + 255) / 256;     // 391
    const int NB_EPB  = (N_EDGES + EPB - 1) / EPB; // 196

    hipMemsetAsync(bucket_count, 0, NBUCK * sizeof(int), stream);
    hipMemsetAsync(out, 0, NSTRUCT * sizeof(float), stream);

    k_pack<<<NB_ATOM, 256, 0, stream>>>(pos, mmv, species, packed);
    k_prep<<<6, 256, 0, stream>>>(embt, Wm1, bm1, Ws1, bs1, c1m, c1s);
    k_bhist<<<NB_EPB, 1024, 0, stream>>>(i_idx, bucket_count);
    k_bscan<<<1, 1024, 0, stream>>>(bucket_count, bucket_start, bucket_cursor);
    k_bscatter<<<NB_EPB, 1024, 0, stream>>>(i_idx, j_idx, bucket_cursor, ij_bucketed);
    k_fused<<<NBUCK, 512, 0, stream>>>(bucket_start, bucket_count, ij_bucketed,
                                       packed, cheb, segbuf);
    k_struct<<<NB_ATOM, 256, 0, stream>>>(segbuf, species, batch, c1s, shift,
                                          Ws1, Ws2, bs2, Ws3, bs3, out);
    dim3 magGrid(NB_ATOM, 9);
    k_mag<<<magGrid, 256, 0, stream>>>(segbuf, packed, species, batch, c1m,
                                       Wm1, Wm2, bm2, Wm3, bm3, out);
}